// Round 6
// baseline (238.875 us; speedup 1.0000x reference)
//
#include <hip/hip_runtime.h>
#include <hip/hip_bf16.h>

typedef __bf16 bf16;
typedef __attribute__((ext_vector_type(8))) __bf16 bf16x8;
typedef __attribute__((ext_vector_type(4))) __bf16 bf16x4;
typedef __attribute__((ext_vector_type(4))) float f32x4;

#define M_TOK 32768   // B*S = 8*4096
#define D_    512
#define N_QKV 1536
#define BK    64
#define SCALE_ 0.125f

#define AS1 __attribute__((address_space(1)))
#define AS3 __attribute__((address_space(3)))

// s_waitcnt with lgkmcnt=15, expcnt=7 (no wait), vmcnt=N  (gfx9 encoding)
#define WAITCNT_VM(N) __builtin_amdgcn_s_waitcnt(0xF70 | ((N) & 0xF) | ((((N) >> 4) & 3) << 14))

// ---------------- fp32 -> bf16 convert (vectorized) ----------------
__global__ __launch_bounds__(256) void cvt_bf16(const float* __restrict__ in,
                                                bf16* __restrict__ out, int n4) {
  int i = blockIdx.x * 256 + threadIdx.x;
  if (i >= n4) return;
  f32x4 v = ((const f32x4*)in)[i];
  bf16x4 o;
  o[0] = (bf16)v[0]; o[1] = (bf16)v[1]; o[2] = (bf16)v[2]; o[3] = (bf16)v[3];
  ((bf16x4*)out)[i] = o;
}

// ---------------- transpose+convert: fp32 in [K][N] -> bf16 out [N][K] ----------------
// PERM=1: head-major column permutation for W_qkv:
//   orig col n (=qkv*512 + h*64 + c) -> out row h*192 + qkv*64 + c
template <int PERM>
__global__ __launch_bounds__(256) void transpose_cvt(const float* __restrict__ in,
                                                     bf16* __restrict__ out,
                                                     int K, int N) {
  __shared__ float tile[32][33];
  int n0 = blockIdx.x * 32, k0 = blockIdx.y * 32;
  int tx = threadIdx.x, ty = threadIdx.y;
  for (int i = 0; i < 32; i += 8)
    tile[ty + i][tx] = in[(size_t)(k0 + ty + i) * N + n0 + tx];
  __syncthreads();
  for (int i = 0; i < 32; i += 8) {
    int n = n0 + ty + i;
    int np = n;
    if (PERM) {
      int h = (n & 511) >> 6, qkv = n >> 9;
      np = h * 192 + qkv * 64 + (n & 63);
    }
    out[(size_t)np * K + k0 + tx] = (bf16)tile[tx][ty + i];
  }
}

// ---------------- fused GEMM1 + per-head softmax ----------------
// A [M,512] bf16, Bt [1536(perm),512] bf16. Block = 128 rows x 192 cols (one head).
// A double-buffered (2 steps ahead), B single-buffered (1 step ahead);
// raw s_barrier + manual vmcnt(4) keeps the A prefetch in flight across barriers.
// Flat grid 2048: id = (rt&7) | (h<<3) | ((rt>>3)<<6)  -> the 8 heads of a
// row-tile are temporally adjacent AND on the same XCD (id%8 == rt%8).
__global__ __launch_bounds__(256) void gemm_qkv_softmax(const bf16* __restrict__ A,
                                                        const bf16* __restrict__ Bt,
                                                        const float* __restrict__ bqkv,
                                                        bf16* __restrict__ O) {
  __shared__ __align__(16) bf16 sA[2][128 * BK];   // 2 x 16 KB
  __shared__ __align__(16) bf16 sB[192 * BK];      // 24 KB

  const int tid = threadIdx.x;
  const int w = tid >> 6;
  const int l = tid & 63;
  const int b = blockIdx.x;
  const int rt = (b & 7) | ((b >> 6) << 3);   // row-tile 0..255
  const int h  = (b >> 3) & 7;                // head 0..7
  const int m0 = rt * 128;
  const int n0 = h * 192;

  f32x4 acc[2][12];
#pragma unroll
  for (int i = 0; i < 2; ++i)
#pragma unroll
    for (int j = 0; j < 12; ++j) {
      f32x4 z = {0.f, 0.f, 0.f, 0.f};
      acc[i][j] = z;
    }

  const int srow = l >> 3;
  const int schunk = ((l & 7) ^ (l >> 3)) * 8;   // XOR-swizzled staged chunk
  const int fr = l & 15;
  const int fkc = l >> 4;
  const int frs = fr & 7;

  auto issue_A = [&](int kt, int pb) {
#pragma unroll
    for (int q = 0; q < 4; ++q) {
      int rowb = w * 32 + q * 8;
      const bf16* gp = A + (size_t)(m0 + rowb + srow) * D_ + kt + schunk;
      __builtin_amdgcn_global_load_lds((AS1 void*)gp, (AS3 void*)&sA[pb][rowb * BK], 16, 0, 0);
    }
  };
  auto issue_B = [&](int kt) {
#pragma unroll
    for (int q = 0; q < 6; ++q) {
      int rowb = w * 48 + q * 8;
      const bf16* gp = Bt + (size_t)(n0 + rowb + srow) * D_ + kt + schunk;
      __builtin_amdgcn_global_load_lds((AS1 void*)gp, (AS3 void*)&sB[rowb * BK], 16, 0, 0);
    }
  };

  issue_A(0, 0);       // FIFO: A0(4), B0(6), A1(4)
  issue_B(0);
  issue_A(BK, 1);

#pragma unroll
  for (int k = 0; k < 8; ++k) {
    if (k < 7) { WAITCNT_VM(4); } else { WAITCNT_VM(0); }
    __builtin_amdgcn_s_barrier();
#pragma unroll
    for (int kk = 0; kk < 2; ++kk) {
      const int sw = (((kk << 2) | fkc) ^ frs) * 8;
      bf16x8 af0 = *(const bf16x8*)&sA[k & 1][(w * 32 + 0  + fr) * BK + sw];
      bf16x8 af1 = *(const bf16x8*)&sA[k & 1][(w * 32 + 16 + fr) * BK + sw];
#pragma unroll
      for (int j = 0; j < 12; ++j) {
        bf16x8 bfj = *(const bf16x8*)&sB[(j * 16 + fr) * BK + sw];
        acc[0][j] = __builtin_amdgcn_mfma_f32_16x16x32_bf16(af0, bfj, acc[0][j], 0, 0, 0);
        acc[1][j] = __builtin_amdgcn_mfma_f32_16x16x32_bf16(af1, bfj, acc[1][j], 0, 0, 0);
      }
    }
    __builtin_amdgcn_s_barrier();
    if (k < 7) issue_B((k + 1) * BK);
    if (k < 6) issue_A((k + 2) * BK, k & 1);
  }

  // biases for this lane's 4 q/k/v columns (col within head = jq*16 + fr)
  float bq[4], bk_[4], bv[4];
#pragma unroll
  for (int jq = 0; jq < 4; ++jq) {
    int c = h * 64 + jq * 16 + fr;
    bq[jq]  = bqkv[c];
    bk_[jq] = bqkv[512 + c];
    bv[jq]  = bqkv[1024 + c];
  }

  const int rbase = (l >> 4) * 4;
#pragma unroll
  for (int i = 0; i < 2; ++i) {
#pragma unroll
    for (int r = 0; r < 4; ++r) {
      float sc[4];
#pragma unroll
      for (int jq = 0; jq < 4; ++jq)
        sc[jq] = (acc[i][jq][r] + bq[jq] - acc[i][jq + 4][r] - bk_[jq]) * SCALE_;
      float mx = fmaxf(fmaxf(sc[0], sc[1]), fmaxf(sc[2], sc[3]));
#pragma unroll
      for (int off = 1; off < 16; off <<= 1) mx = fmaxf(mx, __shfl_xor(mx, off));
      float e[4];
      float sum = 0.f;
#pragma unroll
      for (int jq = 0; jq < 4; ++jq) { e[jq] = __expf(sc[jq] - mx); sum += e[jq]; }
#pragma unroll
      for (int off = 1; off < 16; off <<= 1) sum += __shfl_xor(sum, off);
      float inv = 1.0f / sum;
      int m = m0 + w * 32 + i * 16 + rbase + r;
#pragma unroll
      for (int jq = 0; jq < 4; ++jq) {
        float o = e[jq] * inv * (acc[i][jq + 8][r] + bv[jq]);
        O[(size_t)m * D_ + h * 64 + jq * 16 + fr] = (bf16)o;
      }
    }
  }
}

// ---------------- GEMM2: out = resid + O * Wp^T + bias (fp32 out) ----------------
// Same A-dbuf + raw-barrier pipeline; LDS 48 KB -> 3 blocks/CU.
// Flat grid 1024: id = (rt&7) | (c<<3) | ((rt>>3)<<5): col-blocks of a row-tile
// temporally adjacent + same XCD.
__global__ __launch_bounds__(256) void gemm_bt_f32(const bf16* __restrict__ A,
                                                   const bf16* __restrict__ Bt,
                                                   const float* __restrict__ bias,
                                                   const float* __restrict__ resid,
                                                   float* __restrict__ C) {
  __shared__ __align__(16) bf16 sA[2][128 * BK];   // 2 x 16 KB
  __shared__ __align__(16) bf16 sB[128 * BK];      // 16 KB

  const int tid = threadIdx.x;
  const int w = tid >> 6;
  const int l = tid & 63;
  const int b = blockIdx.x;
  const int rt = (b & 7) | ((b >> 5) << 3);   // row-tile 0..255
  const int c  = (b >> 3) & 3;                // col-block 0..3
  const int m0 = rt * 128;
  const int n0 = c * 128;
  const int wrow = w >> 1, wcol = w & 1;
  const int N = D_;

  f32x4 acc[4][4];
#pragma unroll
  for (int i = 0; i < 4; ++i)
#pragma unroll
    for (int j = 0; j < 4; ++j) {
      f32x4 z = {0.f, 0.f, 0.f, 0.f};
      acc[i][j] = z;
    }

  const int srow = l >> 3;
  const int schunk = ((l & 7) ^ (l >> 3)) * 8;
  const int fr = l & 15;
  const int fkc = l >> 4;
  const int frs = fr & 7;

  auto issue_A = [&](int kt, int pb) {
#pragma unroll
    for (int q = 0; q < 4; ++q) {
      int rowb = w * 32 + q * 8;
      const bf16* gp = A + (size_t)(m0 + rowb + srow) * D_ + kt + schunk;
      __builtin_amdgcn_global_load_lds((AS1 void*)gp, (AS3 void*)&sA[pb][rowb * BK], 16, 0, 0);
    }
  };
  auto issue_B = [&](int kt) {
#pragma unroll
    for (int q = 0; q < 4; ++q) {
      int rowb = w * 32 + q * 8;
      const bf16* gp = Bt + (size_t)(n0 + rowb + srow) * D_ + kt + schunk;
      __builtin_amdgcn_global_load_lds((AS1 void*)gp, (AS3 void*)&sB[rowb * BK], 16, 0, 0);
    }
  };

  issue_A(0, 0);
  issue_B(0);
  issue_A(BK, 1);

#pragma unroll
  for (int k = 0; k < 8; ++k) {
    if (k < 7) { WAITCNT_VM(4); } else { WAITCNT_VM(0); }
    __builtin_amdgcn_s_barrier();
#pragma unroll
    for (int kk = 0; kk < 2; ++kk) {
      const int sw = (((kk << 2) | fkc) ^ frs) * 8;
      bf16x8 af[4], bfr[4];
#pragma unroll
      for (int i = 0; i < 4; ++i)
        af[i] = *(const bf16x8*)&sA[k & 1][(wrow * 64 + i * 16 + fr) * BK + sw];
#pragma unroll
      for (int j = 0; j < 4; ++j)
        bfr[j] = *(const bf16x8*)&sB[(wcol * 64 + j * 16 + fr) * BK + sw];
#pragma unroll
      for (int i = 0; i < 4; ++i)
#pragma unroll
        for (int j = 0; j < 4; ++j)
          acc[i][j] = __builtin_amdgcn_mfma_f32_16x16x32_bf16(af[i], bfr[j], acc[i][j], 0, 0, 0);
    }
    __builtin_amdgcn_s_barrier();
    if (k < 7) issue_B((k + 1) * BK);
    if (k < 6) issue_A((k + 2) * BK, k & 1);
  }

  const int col = l & 15;
  const int rbase = (l >> 4) * 4;
#pragma unroll
  for (int j = 0; j < 4; ++j) {
    int n = n0 + wcol * 64 + j * 16 + col;
    float bv = bias[n];
#pragma unroll
    for (int i = 0; i < 4; ++i) {
#pragma unroll
      for (int r = 0; r < 4; ++r) {
        int m = m0 + wrow * 64 + i * 16 + rbase + r;
        C[(size_t)m * N + n] = acc[i][j][r] + bv + resid[(size_t)m * N + n];
      }
    }
  }
}

extern "C" void kernel_launch(void* const* d_in, const int* in_sizes, int n_in,
                              void* d_out, int out_size, void* d_ws, size_t ws_size,
                              hipStream_t stream) {
  const float* x     = (const float*)d_in[0];   // [32768, 512]
  const float* Wqkv  = (const float*)d_in[1];   // [512, 1536]
  const float* bqkv  = (const float*)d_in[2];   // [1536]
  const float* Wproj = (const float*)d_in[3];   // [512, 512]
  const float* bproj = (const float*)d_in[4];   // [512]
  float* out = (float*)d_out;

  // workspace (~69.2 MB)
  char* ws = (char*)d_ws;
  bf16* Wq_t = (bf16*)ws;                               // [1536,512] perm  1.57 MB
  bf16* Wp_t = (bf16*)(ws + (size_t)N_QKV * D_ * 2);    // [512,512]        0.52 MB
  char* p = ws + (size_t)N_QKV * D_ * 2 + (size_t)D_ * D_ * 2;
  bf16* Xb = (bf16*)p;                                  // [32768,512] bf16 33.6 MB
  bf16* O  = (bf16*)(p + (size_t)M_TOK * D_ * 2);       // [32768,512] bf16 33.6 MB

  transpose_cvt<1><<<dim3(N_QKV / 32, D_ / 32), dim3(32, 8), 0, stream>>>(Wqkv, Wq_t, D_, N_QKV);
  transpose_cvt<0><<<dim3(D_ / 32, D_ / 32), dim3(32, 8), 0, stream>>>(Wproj, Wp_t, D_, D_);

  cvt_bf16<<<(M_TOK * D_ / 4 + 255) / 256, 256, 0, stream>>>(x, Xb, M_TOK * D_ / 4);

  gemm_qkv_softmax<<<2048, 256, 0, stream>>>(Xb, Wq_t, bqkv, O);

  gemm_bt_f32<<<1024, 256, 0, stream>>>(O, Wp_t, bproj, x, out);
}